// Round 1
// baseline (190.097 us; speedup 1.0000x reference)
//
#include <hip/hip_runtime.h>
#include <hip/hip_bf16.h>

#define N_  16384
#define D_  128
#define M1_ 64
#define K_  8

typedef short short8 __attribute__((ext_vector_type(8)));
typedef float f32x4  __attribute__((ext_vector_type(4)));

__device__ __forceinline__ ushort f2bf(float f) {
    union { float f; unsigned u; } un; un.f = f;
    unsigned u = un.u;
    // round-to-nearest-even bf16 (inputs are finite normals)
    return (ushort)((u + 0x7fffu + ((u >> 16) & 1u)) >> 16);
}

// ---- prep: x (fp32) -> bf16, vectorized float4 ----
__global__ void prep_x_kernel(const float* __restrict__ x, ushort* __restrict__ xbf) {
    int i = blockIdx.x * 256 + threadIdx.x;          // i < N_*D_/4
    float4 f = ((const float4*)x)[i];
    ushort4 o;
    o.x = f2bf(f.x); o.y = f2bf(f.y); o.z = f2bf(f.z); o.w = f2bf(f.w);
    ((ushort4*)xbf)[i] = o;
}

// ---- prep: W = (w1p - w1n) with W[j,m,j]=0, -> bf16 ----
__global__ void prep_w_kernel(const float* __restrict__ wp, const float* __restrict__ wn,
                              ushort* __restrict__ wbf) {
    int i = blockIdx.x * 256 + threadIdx.x;          // i < D_*M1_*D_/4
    int base = i * 4;
    int j  = base >> 13;                             // / (M1_*D_)
    int d0 = base & (D_ - 1);
    float4 p = ((const float4*)wp)[i];
    float4 n = ((const float4*)wn)[i];
    float4 w;
    w.x = p.x - n.x; w.y = p.y - n.y; w.z = p.z - n.z; w.w = p.w - n.w;
    if (j == d0    ) w.x = 0.f;
    if (j == d0 + 1) w.y = 0.f;
    if (j == d0 + 2) w.z = 0.f;
    if (j == d0 + 3) w.w = 0.f;
    ushort4 o;
    o.x = f2bf(w.x); o.y = f2bf(w.y); o.z = f2bf(w.z); o.w = f2bf(w.w);
    ((ushort4*)wbf)[i] = o;
}

// ---- prep: b = b1p-b1n ; v[j,m] = sum_k w3[j,k]*w2[k,m] ; c[j] = sum_k w3[j,k]*b2[k] ----
__global__ void prep_vb_kernel(const float* __restrict__ b1p, const float* __restrict__ b1n,
                               const float* __restrict__ w2,  const float* __restrict__ b2,
                               const float* __restrict__ w3,
                               float* __restrict__ bv, float* __restrict__ vv,
                               float* __restrict__ cv) {
    int idx = blockIdx.x * 256 + threadIdx.x;        // idx < D_*M1_
    int j = idx >> 6, m = idx & 63;
    float v = 0.f;
    for (int k = 0; k < K_; k++) v += w3[j * K_ + k] * w2[k * M1_ + m];
    vv[idx] = v;
    bv[idx] = b1p[idx] - b1n[idx];
    if (m == 0) {
        float c = 0.f;
        for (int k = 0; k < K_; k++) c += w3[j * K_ + k] * b2[k];
        cv[j] = c;
    }
}

// ---- main: per block: 64 n-rows x one j (all 64 m), fused sigmoid/v-reduce epilogue ----
#define LDS_PITCH 136   // 128 + 8 bf16 pad -> 2-way bank aliasing only (free)

__global__ __launch_bounds__(256) void main_mfma(
    const ushort* __restrict__ xbf, const ushort* __restrict__ wbf,
    const float* __restrict__ bvec, const float* __restrict__ vvec,
    const float* __restrict__ cvec, float* __restrict__ out) {
    __shared__ ushort lds_x[64 * LDS_PITCH];
    __shared__ ushort lds_w[64 * LDS_PITCH];
    const int tid = threadIdx.x;
    const int j   = blockIdx.y;
    const int n0  = blockIdx.x * 64;

    const ushort* xg = xbf + (size_t)n0 * D_;        // 64x128 bf16, contiguous
    const ushort* wg = wbf + (size_t)j * (M1_ * D_); // 64x128 bf16, contiguous
    for (int u = tid; u < 1024; u += 256) {          // 1024 x 16B each array
        int row = u >> 4, c = u & 15;
        uint4 xv = ((const uint4*)xg)[u];
        uint4 wv = ((const uint4*)wg)[u];
        *(uint4*)&lds_x[row * LDS_PITCH + c * 8] = xv;
        *(uint4*)&lds_w[row * LDS_PITCH + c * 8] = wv;
    }
    __syncthreads();

    const int wave = tid >> 6, lane = tid & 63;
    const int quad = lane >> 4, col = lane & 15;

    f32x4 acc[4] = {};   // 4 m-tiles of 16, rows = wave*16..+15
    const ushort* xrow = &lds_x[(wave * 16 + col) * LDS_PITCH];
    for (int ks = 0; ks < 4; ks++) {
        short8 a = *(const short8*)&xrow[ks * 32 + quad * 8];
        for (int mt = 0; mt < 4; mt++) {
            short8 b = *(const short8*)&lds_w[(mt * 16 + col) * LDS_PITCH + ks * 32 + quad * 8];
            acc[mt] = __builtin_amdgcn_mfma_f32_16x16x32_bf16(a, b, acc[mt], 0, 0, 0);
        }
    }

    // epilogue: h = sigmoid(acc + b[j,m]); partial[r] = sum_m v[j,m]*h
    float partial[4] = {0.f, 0.f, 0.f, 0.f};
    for (int mt = 0; mt < 4; mt++) {
        int m = mt * 16 + col;
        float bb = bvec[j * M1_ + m];
        float vm = vvec[j * M1_ + m];
        for (int r = 0; r < 4; r++) {
            float t = acc[mt][r] + bb;
            float s = 1.0f / (1.0f + __expf(-t));
            partial[r] += s * vm;
        }
    }
    // reduce across the 16 lanes of each quad (masks 1..8 keep quad fixed)
    for (int r = 0; r < 4; r++) {
        float p = partial[r];
        p += __shfl_xor(p, 1);
        p += __shfl_xor(p, 2);
        p += __shfl_xor(p, 4);
        p += __shfl_xor(p, 8);
        partial[r] = p;
    }
    if (col < 4) {
        int n = n0 + wave * 16 + quad * 4 + col;
        float p = (col == 0) ? partial[0] : (col == 1) ? partial[1]
                : (col == 2) ? partial[2] : partial[3];
        out[(size_t)n * D_ + j] = p + cvec[j];
    }
}

// ---- fp32 fallback (only if workspace is too small for bf16 staging) ----
__global__ void fallback_kernel(const float* __restrict__ x,
                                const float* __restrict__ w1p, const float* __restrict__ b1p,
                                const float* __restrict__ w1n, const float* __restrict__ b1n,
                                const float* __restrict__ w2,  const float* __restrict__ b2,
                                const float* __restrict__ w3,  float* __restrict__ out) {
    int n = blockIdx.x, j = blockIdx.y, m = threadIdx.x;  // 64 threads
    const float* xr = x + (size_t)n * D_;
    const float* wp = w1p + ((size_t)j * M1_ + m) * D_;
    const float* wn = w1n + ((size_t)j * M1_ + m) * D_;
    float acc = 0.f;
    for (int d = 0; d < D_; d++) {
        if (d == j) continue;
        acc += xr[d] * (wp[d] - wn[d]);
    }
    acc += b1p[j * M1_ + m] - b1n[j * M1_ + m];
    float h = 1.f / (1.f + __expf(-acc));
    float vm = 0.f;
    for (int k = 0; k < K_; k++) vm += w3[j * K_ + k] * w2[k * M1_ + m];
    float p = h * vm;
    for (int off = 1; off < 64; off <<= 1) p += __shfl_xor(p, off);
    if (m == 0) {
        float c = 0.f;
        for (int k = 0; k < K_; k++) c += w3[j * K_ + k] * b2[k];
        out[(size_t)n * D_ + j] = p + c;
    }
}

extern "C" void kernel_launch(void* const* d_in, const int* in_sizes, int n_in,
                              void* d_out, int out_size, void* d_ws, size_t ws_size,
                              hipStream_t stream) {
    const float* x   = (const float*)d_in[0];
    const float* w1p = (const float*)d_in[1];
    const float* b1p = (const float*)d_in[2];
    const float* w1n = (const float*)d_in[3];
    const float* b1n = (const float*)d_in[4];
    const float* w2  = (const float*)d_in[5];
    const float* b2  = (const float*)d_in[6];
    const float* w3  = (const float*)d_in[7];
    float* out = (float*)d_out;

    const size_t off_x = 0;
    const size_t off_w = off_x + (size_t)N_ * D_ * 2;          // x bf16: 4 MB
    const size_t off_b = off_w + (size_t)D_ * M1_ * D_ * 2;    // W bf16: 2 MB
    const size_t off_v = off_b + (size_t)D_ * M1_ * 4;
    const size_t off_c = off_v + (size_t)D_ * M1_ * 4;
    const size_t need  = off_c + (size_t)D_ * 4;

    if (ws_size < need) {
        fallback_kernel<<<dim3(N_, D_), 64, 0, stream>>>(x, w1p, b1p, w1n, b1n, w2, b2, w3, out);
        return;
    }

    ushort* xbf = (ushort*)((char*)d_ws + off_x);
    ushort* wbf = (ushort*)((char*)d_ws + off_w);
    float*  bv  = (float*)((char*)d_ws + off_b);
    float*  vv  = (float*)((char*)d_ws + off_v);
    float*  cv  = (float*)((char*)d_ws + off_c);

    prep_x_kernel <<<(N_ * D_ / 4) / 256, 256, 0, stream>>>(x, xbf);
    prep_w_kernel <<<(D_ * M1_ * D_ / 4) / 256, 256, 0, stream>>>(w1p, w1n, wbf);
    prep_vb_kernel<<<(D_ * M1_) / 256, 256, 0, stream>>>(b1p, b1n, w2, b2, w3, bv, vv, cv);
    main_mfma<<<dim3(N_ / 64, D_), 256, 0, stream>>>(xbf, wbf, bv, vv, cv, out);
}

// Round 3
// 170.069 us; speedup vs baseline: 1.1178x; 1.1178x over previous
//
#include <hip/hip_runtime.h>
#include <hip/hip_bf16.h>

#define N_  16384
#define D_  128
#define M1_ 64
#define K_  8

typedef short short8 __attribute__((ext_vector_type(8)));
typedef float f32x4  __attribute__((ext_vector_type(4)));

__device__ __forceinline__ ushort f2bf(float f) {
    union { float f; unsigned u; } un; un.f = f;
    unsigned u = un.u;
    return (ushort)((u + 0x7fffu + ((u >> 16) & 1u)) >> 16);
}

// ---- fused prep: one launch does x->bf16, W->bf16 (masked), and b/v/c fold ----
// grid: [0,2048) x-cast | [2048,3072) W | [3072,3104) vb
__global__ void prep_all(const float* __restrict__ x,
                         const float* __restrict__ w1p, const float* __restrict__ b1p,
                         const float* __restrict__ w1n, const float* __restrict__ b1n,
                         const float* __restrict__ w2,  const float* __restrict__ b2,
                         const float* __restrict__ w3,
                         ushort* __restrict__ xbf, ushort* __restrict__ wbf,
                         float* __restrict__ bn, float* __restrict__ vv,
                         float* __restrict__ cv) {
    int bx = blockIdx.x;
    if (bx < 2048) {                                   // x: N_*D_/4 / 256 = 2048
        int i = bx * 256 + threadIdx.x;
        float4 f = ((const float4*)x)[i];
        ushort4 o;
        o.x = f2bf(f.x); o.y = f2bf(f.y); o.z = f2bf(f.z); o.w = f2bf(f.w);
        ((ushort4*)xbf)[i] = o;
    } else if (bx < 3072) {                            // W: D_*M1_*D_/4 / 256 = 1024
        int i = (bx - 2048) * 256 + threadIdx.x;
        int base = i * 4;
        int j  = base >> 13;                           // / (M1_*D_)
        int d0 = base & (D_ - 1);
        float4 p = ((const float4*)w1p)[i];
        float4 n = ((const float4*)w1n)[i];
        float4 w;
        w.x = p.x - n.x; w.y = p.y - n.y; w.z = p.z - n.z; w.w = p.w - n.w;
        if (j == d0    ) w.x = 0.f;
        if (j == d0 + 1) w.y = 0.f;
        if (j == d0 + 2) w.z = 0.f;
        if (j == d0 + 3) w.w = 0.f;
        ushort4 o;
        o.x = f2bf(w.x); o.y = f2bf(w.y); o.z = f2bf(w.z); o.w = f2bf(w.w);
        ((ushort4*)wbf)[i] = o;
    } else {                                           // vb: D_*M1_ / 256 = 32
        int idx = (bx - 3072) * 256 + threadIdx.x;
        int j = idx >> 6, m = idx & 63;
        float v = 0.f;
        for (int k = 0; k < K_; k++) v += w3[j * K_ + k] * w2[k * M1_ + m];
        vv[idx] = v;
        bn[idx] = -(b1p[idx] - b1n[idx]);              // negated bias for sigmoid
        if (m == 0) {
            float c = 0.f;
            for (int k = 0; k < K_; k++) c += w3[j * K_ + k] * b2[k];
            cv[j] = c;
        }
    }
}

// ---- main: grid (32 nblk, 128 j); W-tile in registers, persistent over 8 n-subtiles.
// No LDS, no __syncthreads. A-fragments direct from global (L2-resident by XCD slice).
// NOTE: no min-waves clamp — a 128-VGPR cap (256,4) forced the allocator into an
// untested spill regime and round 2 died at launch; let it pick its own count.
__global__ __launch_bounds__(256) void main_mfma(
    const ushort* __restrict__ xbf, const ushort* __restrict__ wbf,
    const float* __restrict__ bnvec, const float* __restrict__ vvec,
    const float* __restrict__ cvec, float* __restrict__ out) {
    const int tid  = threadIdx.x;
    const int wave = tid >> 6, lane = tid & 63;
    const int quad = lane >> 4, col = lane & 15;
    const int j    = blockIdx.y;
    const int nblk = blockIdx.x;                       // 0..31, fast dim -> XCD = nblk%8

    // B-fragments (W) in registers, loaded once per block: 16 x short8 = 64 VGPRs
    short8 bw[4][4];                                   // [mt][ks]
    const ushort* wg = wbf + (size_t)j * (M1_ * D_);
    #pragma unroll
    for (int mt = 0; mt < 4; mt++)
        #pragma unroll
        for (int ks = 0; ks < 4; ks++)
            bw[mt][ks] = *(const short8*)&wg[(mt * 16 + col) * D_ + ks * 32 + quad * 8];

    // per-lane epilogue constants (m = mt*16 + col)
    float bneg[4], vm[4];
    #pragma unroll
    for (int mt = 0; mt < 4; mt++) {
        int m = mt * 16 + col;
        bneg[mt] = bnvec[j * M1_ + m];
        vm[mt]   = vvec[j * M1_ + m];
    }
    const float cj = cvec[j];

    // A-fragment base: this wave's 16 n-rows, row index = col (A's M dim)
    const int rowbase = nblk * 512 + wave * 16 + col;
    const ushort* xr0 = xbf + (size_t)rowbase * D_ + quad * 8;

    for (int st = 0; st < 8; st++) {
        const ushort* xr = xr0 + (size_t)st * 64 * D_;
        short8 a[4];
        #pragma unroll
        for (int ks = 0; ks < 4; ks++)
            a[ks] = *(const short8*)&xr[ks * 32];

        f32x4 acc[4] = {};
        #pragma unroll
        for (int ks = 0; ks < 4; ks++)
            #pragma unroll
            for (int mt = 0; mt < 4; mt++)
                acc[mt] = __builtin_amdgcn_mfma_f32_16x16x32_bf16(a[ks], bw[mt][ks], acc[mt], 0, 0, 0);

        // epilogue: s = 1/(1+exp(bneg - acc)); partial[r] = sum_m s*v[m]
        float partial[4] = {0.f, 0.f, 0.f, 0.f};
        #pragma unroll
        for (int mt = 0; mt < 4; mt++) {
            #pragma unroll
            for (int r = 0; r < 4; r++) {
                float u = bneg[mt] - acc[mt][r];
                float e = __expf(u);
                float s = __builtin_amdgcn_rcpf(1.0f + e);
                partial[r] = fmaf(s, vm[mt], partial[r]);
            }
        }
        // reduce over the 16 cols (m) within each quad
        #pragma unroll
        for (int r = 0; r < 4; r++) {
            float p = partial[r];
            p += __shfl_xor(p, 1);
            p += __shfl_xor(p, 2);
            p += __shfl_xor(p, 4);
            p += __shfl_xor(p, 8);
            partial[r] = p;
        }
        if (col < 4) {
            int n = nblk * 512 + st * 64 + wave * 16 + quad * 4 + col;
            float p = (col == 0) ? partial[0] : (col == 1) ? partial[1]
                    : (col == 2) ? partial[2] : partial[3];
            out[(size_t)n * D_ + j] = p + cj;
        }
    }
}

// ---- fp32 fallback (workspace too small) ----
__global__ void fallback_kernel(const float* __restrict__ x,
                                const float* __restrict__ w1p, const float* __restrict__ b1p,
                                const float* __restrict__ w1n, const float* __restrict__ b1n,
                                const float* __restrict__ w2,  const float* __restrict__ b2,
                                const float* __restrict__ w3,  float* __restrict__ out) {
    int n = blockIdx.x, j = blockIdx.y, m = threadIdx.x;
    const float* xr = x + (size_t)n * D_;
    const float* wp = w1p + ((size_t)j * M1_ + m) * D_;
    const float* wn = w1n + ((size_t)j * M1_ + m) * D_;
    float acc = 0.f;
    for (int d = 0; d < D_; d++) {
        if (d == j) continue;
        acc += xr[d] * (wp[d] - wn[d]);
    }
    acc += b1p[j * M1_ + m] - b1n[j * M1_ + m];
    float h = 1.f / (1.f + __expf(-acc));
    float vmv = 0.f;
    for (int k = 0; k < K_; k++) vmv += w3[j * K_ + k] * w2[k * M1_ + m];
    float p = h * vmv;
    for (int off = 1; off < 64; off <<= 1) p += __shfl_xor(p, off);
    if (m == 0) {
        float c = 0.f;
        for (int k = 0; k < K_; k++) c += w3[j * K_ + k] * b2[k];
        out[(size_t)n * D_ + j] = p + c;
    }
}

extern "C" void kernel_launch(void* const* d_in, const int* in_sizes, int n_in,
                              void* d_out, int out_size, void* d_ws, size_t ws_size,
                              hipStream_t stream) {
    const float* x   = (const float*)d_in[0];
    const float* w1p = (const float*)d_in[1];
    const float* b1p = (const float*)d_in[2];
    const float* w1n = (const float*)d_in[3];
    const float* b1n = (const float*)d_in[4];
    const float* w2  = (const float*)d_in[5];
    const float* b2  = (const float*)d_in[6];
    const float* w3  = (const float*)d_in[7];
    float* out = (float*)d_out;

    const size_t off_x = 0;
    const size_t off_w = off_x + (size_t)N_ * D_ * 2;          // x bf16: 4 MB
    const size_t off_b = off_w + (size_t)D_ * M1_ * D_ * 2;    // W bf16: 2 MB
    const size_t off_v = off_b + (size_t)D_ * M1_ * 4;
    const size_t off_c = off_v + (size_t)D_ * M1_ * 4;
    const size_t need  = off_c + (size_t)D_ * 4;

    if (ws_size < need) {
        fallback_kernel<<<dim3(N_, D_), 64, 0, stream>>>(x, w1p, b1p, w1n, b1n, w2, b2, w3, out);
        return;
    }

    ushort* xbf = (ushort*)((char*)d_ws + off_x);
    ushort* wbf = (ushort*)((char*)d_ws + off_w);
    float*  bn  = (float*)((char*)d_ws + off_b);
    float*  vv  = (float*)((char*)d_ws + off_v);
    float*  cv  = (float*)((char*)d_ws + off_c);

    prep_all<<<3104, 256, 0, stream>>>(x, w1p, b1p, w1n, b1n, w2, b2, w3,
                                       xbf, wbf, bn, vv, cv);
    main_mfma<<<dim3(32, 128), 256, 0, stream>>>(xbf, wbf, bn, vv, cv, out);
}